// Round 3
// baseline (496.656 us; speedup 1.0000x reference)
//
#include <hip/hip_runtime.h>
#include <hip/hip_bf16.h>
#include <hip/hip_cooperative_groups.h>

namespace cg = cooperative_groups;

typedef short v8s __attribute__((ext_vector_type(8)));
typedef float v4f __attribute__((ext_vector_type(4)));

#define KSPLIT 4

// ---- dual-dtype element access (f32m: 0 = bf16, 1 = f32) ----
static __device__ __forceinline__ float ldv(const void* p, size_t i, int f32m) {
    if (f32m) return ((const float*)p)[i];
    return __bfloat162float(((const __hip_bfloat16*)p)[i]);
}
static __device__ __forceinline__ void stv(void* p, size_t i, float v, int f32m) {
    if (f32m) ((float*)p)[i] = v;
    else ((__hip_bfloat16*)p)[i] = __float2bfloat16(v);
}
static __device__ __forceinline__ unsigned short f2bu(float x) {
    __hip_bfloat16 h = __float2bfloat16(x);
    return *(unsigned short*)&h;
}
static __device__ __forceinline__ float bu2f(unsigned short u) {
    return __uint_as_float(((unsigned)u) << 16);
}
// paired (2-element) load: f32 -> float2, bf16 -> ushort2
static __device__ __forceinline__ void ld2(const void* p, size_t i, int f32m, float* o) {
    if (f32m) {
        float2 v = *(const float2*)((const float*)p + i);
        o[0] = v.x; o[1] = v.y;
    } else {
        unsigned u = *(const unsigned*)((const unsigned short*)p + i);
        o[0] = bu2f((unsigned short)(u & 0xffffu));
        o[1] = bu2f((unsigned short)(u >> 16));
    }
}

// Robust scalar decode: handles int32, float32, or bf16-in-low-16 encodings.
static __device__ __forceinline__ float decode_scalar(const void* p) {
    unsigned u = *(const unsigned*)p;
    unsigned e32 = (u >> 23) & 0xff;
    if (e32 >= 97 && e32 <= 160) return __uint_as_float(u);
    unsigned lo = u & 0xffffu;
    unsigned e16 = (lo >> 7) & 0xff;
    if ((u >> 16) == 0 && e16 >= 97 && e16 <= 160)
        return __uint_as_float(lo << 16);
    return (float)(int)u;
}

// Per-block dtype sniff (deterministic; contains a barrier — call unconditionally
// on a block-uniform path).
static __device__ __forceinline__ int block_sniff(const void* feat) {
    const __hip_bfloat16* p = (const __hip_bfloat16*)feat;
    float v = __bfloat162float(p[threadIdx.x & 255]);
    int bad = !(fabsf(v) < 1e10f);
    return __syncthreads_or(bad) ? 1 : 0;
}

__device__ __forceinline__ float wave_sum(float v) {
    #pragma unroll
    for (int o = 32; o > 0; o >>= 1) v += __shfl_down(v, o, 64);
    return v;
}
__device__ __forceinline__ float wave_max(float v) {
    #pragma unroll
    for (int o = 32; o > 0; o >>= 1) v = fmaxf(v, __shfl_down(v, o, 64));
    return v;
}

// async global->LDS, 16B per lane, LDS dst = wave-uniform base + lane*16
static __device__ __forceinline__ void ld16(unsigned short* lds, const unsigned short* g) {
    __builtin_amdgcn_global_load_lds(
        (const __attribute__((address_space(1))) unsigned int*)g,
        (__attribute__((address_space(3))) unsigned int*)lds,
        16, 0, 0);
}

// ===================== cooperative mega-kernel =====================

struct MegaArgs {
    const void* feat; const int* labels; const void* W; const void* bias;
    const void* ave; const void* cov; const void* amount; const void* ratiop;
    void* out;
    unsigned long long off_y, off_ave, off_cov, off_amt;
    int* counts; int* offs; int* rowsg; float* T3p; float* lsum; int* lcnt;
    float* partY; float* partT1; float* partT2;
    unsigned short* featb; unsigned short* Wb; unsigned short* W2b;
    unsigned short* Cb; unsigned short* Gb;
    int Nn, C, A, Cpad, A8, total;
    unsigned long long NC;
};

__global__ __launch_bounds__(256, 2) void isda_mega(MegaArgs p) {
    __shared__ union {
        struct { int h[1024]; int o[1024]; int cur[1024]; } s1;                 // 12 KB
        struct { unsigned short sA[3][10240]; int sLab[64]; } s3;               // 61,696 B
        struct { float sb[4]; float sM; float sLabVal; } s4;                    // 24 B
    } sh;

    cg::grid_group grid = cg::this_grid();
    int tid = threadIdx.x;
    int lane = tid & 63, wid = tid >> 6;
    int f32m = block_sniff(p.feat);

    // -------- phase 1: featb conversion (all blocks) + sort (block 0) --------
    for (long long i = ((long long)blockIdx.x * 256 + tid) * 8; i < p.total;
         i += (long long)gridDim.x * 2048) {
        if (f32m) {
            const float* f = (const float*)p.feat + i;
            unsigned short rr[8];
            #pragma unroll
            for (int u2 = 0; u2 < 8; ++u2) rr[u2] = f2bu(f[u2]);
            *(v8s*)(p.featb + i) = *(v8s*)rr;
        } else {
            *(v8s*)(p.featb + i) = *(const v8s*)((const unsigned short*)p.feat + i);
        }
    }
    if (blockIdx.x == 0) {
        for (int k = tid; k < 1024; k += 256) sh.s1.h[k] = 0;
        __syncthreads();
        for (int i = tid; i < p.Nn; i += 256) atomicAdd(&sh.s1.h[p.labels[i]], 1);
        __syncthreads();
        int a0 = sh.s1.h[4 * tid], a1 = sh.s1.h[4 * tid + 1];
        int a2 = sh.s1.h[4 * tid + 2], a3 = sh.s1.h[4 * tid + 3];
        int tsum = a0 + a1 + a2 + a3;
        sh.s1.o[tid] = tsum;
        __syncthreads();
        for (int d = 1; d < 256; d <<= 1) {
            int v = (tid >= d) ? sh.s1.o[tid - d] : 0;
            __syncthreads();
            sh.s1.o[tid] += v;
            __syncthreads();
        }
        int texcl = sh.s1.o[tid] - tsum;
        int e0 = texcl, e1 = e0 + a0, e2 = e1 + a1, e3 = e2 + a2;
        p.counts[4 * tid] = a0; p.counts[4 * tid + 1] = a1;
        p.counts[4 * tid + 2] = a2; p.counts[4 * tid + 3] = a3;
        p.offs[4 * tid] = e0; p.offs[4 * tid + 1] = e1;
        p.offs[4 * tid + 2] = e2; p.offs[4 * tid + 3] = e3;
        sh.s1.cur[4 * tid] = e0; sh.s1.cur[4 * tid + 1] = e1;
        sh.s1.cur[4 * tid + 2] = e2; sh.s1.cur[4 * tid + 3] = e3;
        __syncthreads();
        for (int i = tid; i < p.Nn; i += 256) {
            int pos = atomicAdd(&sh.s1.cur[p.labels[i]], 1);
            p.rowsg[pos] = i;
        }
        if (tid == 0) { *p.lsum = 0.f; *p.lcnt = 0; }
    }
    __threadfence();
    grid.sync();

    // -------- phase 2: finalize stats (grid-strided over C * A/512 units) ----
    {
        int NCH = p.A >> 9;
        int units = p.C * NCH;
        for (int u = blockIdx.x; u < units; u += gridDim.x) {
            int chunk = u % NCH, c = u / NCH;
            int a = (chunk * 256 + tid) * 2;
            size_t idx = (size_t)c * p.A + a;
            int cnti = p.counts[c];
            int start = p.offs[c];
            float s1v[2] = {0.f, 0.f}, s2v[2] = {0.f, 0.f};
            for (int i = 0; i < cnti; ++i) {
                unsigned uu = *(const unsigned*)(p.featb + (size_t)p.rowsg[start + i] * p.A + a);
                float x0 = bu2f((unsigned short)(uu & 0xffffu));
                float x1 = bu2f((unsigned short)(uu >> 16));
                s1v[0] += x0; s2v[0] += x0 * x0;
                s1v[1] += x1; s2v[1] += x1 * x1;
            }
            float cnt = (float)cnti;
            float denomv = cnti > 0 ? cnt : 1.f;
            float amt = ldv(p.amount, c, f32m);
            float tot = cnt + amt;
            float w = tot > 0.f ? (cnt / tot) : 0.f;   // nan_to_num(0/0) -> 0
            float av[2], cvv[2], wvv[2];
            ld2(p.ave, idx, f32m, av);
            ld2(p.cov, idx, f32m, cvv);
            ld2(p.W, idx, f32m, wvv);
            unsigned short cb2[2], gb2[2];
            float t3s = 0.f;
            #pragma unroll
            for (int k = 0; k < 2; ++k) {
                float mean = s1v[k] / denomv;
                float var = fmaxf((s2v[k] - cnt * mean * mean) / denomv, 0.f);
                float d = av[k] - mean;
                float ncv = cvv[k] * (1.f - w) + var * w + w * (1.f - w) * d * d;
                float nav = av[k] * (1.f - w) + mean * w;
                stv(p.out, p.off_cov + idx + k, ncv, f32m);
                stv(p.out, p.off_ave + idx + k, nav, f32m);
                cb2[k] = f2bu(ncv);
                gb2[k] = f2bu(ncv * wvv[k]);
                t3s += wvv[k] * wvv[k] * ncv;
            }
            *(unsigned*)(p.Wb + idx)  = (unsigned)f2bu(wvv[0]) | ((unsigned)f2bu(wvv[1]) << 16);
            *(unsigned*)(p.W2b + idx) = (unsigned)f2bu(wvv[0] * wvv[0]) | ((unsigned)f2bu(wvv[1] * wvv[1]) << 16);
            *(unsigned*)(p.Cb + idx)  = (unsigned)cb2[0] | ((unsigned)cb2[1] << 16);
            *(unsigned*)(p.Gb + idx)  = (unsigned)gb2[0] | ((unsigned)gb2[1] << 16);
            if (a == 0) stv(p.out, p.off_amt + c, amt + cnt, f32m);
            float s = wave_sum(t3s);
            if (lane == 0) sh.s4.sb[wid] = s;
            __syncthreads();
            if (tid == 0)
                p.T3p[(size_t)c * p.A8 + chunk] = sh.s4.sb[0] + sh.s4.sb[1] + sh.s4.sb[2] + sh.s4.sb[3];
            __syncthreads();
        }
    }
    __threadfence();
    grid.sync();

    // -------- phase 3: triple GEMM (R2's proven 3-buffer counted-vmcnt) ------
    {
        int gx = p.Cpad >> 6, gy = p.Nn >> 6;
        int vtot = gx * gy * KSPLIT;
        int kslice = p.A / KSPLIT;
        int NIT = kslice / 32;
        for (int vb = blockIdx.x; vb < vtot; vb += gridDim.x) {
            int x = vb % gx, y = (vb / gx) % gy, z = vb / (gx * gy);
            __syncthreads();   // LDS reuse guard (union + multi-vb)
            if (tid < 64) sh.s3.sLab[tid] = p.labels[y * 64 + tid];
            __syncthreads();
            int n0 = y * 64, j0 = x * 64;
            int k0 = z * kslice;
            int r = lane & 15, q = lane >> 4;
            int fr = wid * 16 + r;
            const unsigned short* pF = p.featb + (size_t)(n0 + fr) * p.A + k0 + q * 8;
            int lab = sh.s3.sLab[fr];
            const unsigned short* pC = p.Cb + (size_t)lab * p.A + k0 + q * 8;
            const unsigned short* pG = p.Gb + (size_t)lab * p.A + k0 + q * 8;
            const unsigned short* pW = p.Wb + (size_t)(j0 + fr) * p.A + k0 + q * 8;
            const unsigned short* pQ = p.W2b + (size_t)(j0 + fr) * p.A + k0 + q * 8;

            v4f aY[4] = {{0,0,0,0},{0,0,0,0},{0,0,0,0},{0,0,0,0}};
            v4f aT1[4] = {{0,0,0,0},{0,0,0,0},{0,0,0,0},{0,0,0,0}};
            v4f aT2[4] = {{0,0,0,0},{0,0,0,0},{0,0,0,0},{0,0,0,0}};

            #define STAGE3(b) do { \
                ld16(&sh.s3.sA[b][0    + wid * 512], pF); \
                ld16(&sh.s3.sA[b][2048 + wid * 512], pC); \
                ld16(&sh.s3.sA[b][4096 + wid * 512], pG); \
                ld16(&sh.s3.sA[b][6144 + wid * 512], pW); \
                ld16(&sh.s3.sA[b][8192 + wid * 512], pQ); \
                pF += 32; pC += 32; pG += 32; pW += 32; pQ += 32; } while (0)

            STAGE3(0);
            STAGE3(1);

            for (int it = 0; it < NIT; ++it) {
                int bcur = it % 3;
                // outstanding here: stage(it) + stage(it+1) = 10 DMAs (5 on last iter)
                if (it + 1 < NIT) asm volatile("s_waitcnt vmcnt(5)\n\ts_barrier" ::: "memory");
                else              asm volatile("s_waitcnt vmcnt(0)\n\ts_barrier" ::: "memory");
                if (it + 2 < NIT) { STAGE3((it + 2) % 3); }
                v8s f  = *(v8s*)&sh.s3.sA[bcur][0    + wid * 512 + lane * 8];
                v8s c2 = *(v8s*)&sh.s3.sA[bcur][2048 + wid * 512 + lane * 8];
                v8s g2 = *(v8s*)&sh.s3.sA[bcur][4096 + wid * 512 + lane * 8];
                #pragma unroll
                for (int t = 0; t < 4; ++t) {
                    v8s w  = *(v8s*)&sh.s3.sA[bcur][6144 + t * 512 + lane * 8];
                    v8s w2 = *(v8s*)&sh.s3.sA[bcur][8192 + t * 512 + lane * 8];
                    aY[t]  = __builtin_amdgcn_mfma_f32_16x16x32_bf16(f,  w,  aY[t],  0, 0, 0);
                    aT1[t] = __builtin_amdgcn_mfma_f32_16x16x32_bf16(c2, w2, aT1[t], 0, 0, 0);
                    aT2[t] = __builtin_amdgcn_mfma_f32_16x16x32_bf16(g2, w,  aT2[t], 0, 0, 0);
                }
            }
            #undef STAGE3

            // C/D layout: col = lane&15, row = (lane>>4)*4 + reg.
            float* pY = p.partY + (size_t)z * p.NC;
            float* p1 = p.partT1 + (size_t)z * p.NC;
            float* p2 = p.partT2 + (size_t)z * p.NC;
            int quad = lane >> 4, colb = lane & 15;
            #pragma unroll
            for (int t = 0; t < 4; ++t) {
                int j = j0 + t * 16 + colb;
                #pragma unroll
                for (int rr2 = 0; rr2 < 4; ++rr2) {
                    int n = n0 + wid * 16 + quad * 4 + rr2;
                    size_t idx = (size_t)n * p.Cpad + j;
                    pY[idx] = aY[t][rr2];
                    p1[idx] = aT1[t][rr2];
                    p2[idx] = aT2[t][rr2];
                }
            }
        }
    }
    __threadfence();
    grid.sync();

    // -------- phase 4: epilogue + row loss + mean (one row per block) --------
    {
        float ratio = decode_scalar(p.ratiop);
        int nu = p.Cpad >> 8;
        for (int n = blockIdx.x; n < p.Nn; n += gridDim.x) {
            __syncthreads();
            int lab = p.labels[n];
            float t3 = 0.f;
            for (int i = 0; i < p.A8; ++i) t3 += p.T3p[(size_t)lab * p.A8 + i];
            float vals[8];
            float m = -3.4e38f;
            for (int u = 0; u < nu; ++u) {
                int j = u * 256 + tid;
                float v = -3.4e38f;
                if (j < p.C) {
                    size_t idx = (size_t)n * p.Cpad + j;
                    float y = 0.f, t1 = 0.f, t2 = 0.f;
                    #pragma unroll
                    for (int zz = 0; zz < KSPLIT; ++zz) {
                        y  += p.partY[zz * p.NC + idx];
                        t1 += p.partT1[zz * p.NC + idx];
                        t2 += p.partT2[zz * p.NC + idx];
                    }
                    y += ldv(p.bias, j, f32m);
                    stv(p.out, p.off_y + (size_t)n * p.C + j, y, f32m);
                    v = y + 0.5f * ratio * (t1 - 2.f * t2 + t3);
                    if (j == lab) sh.s4.sLabVal = v;
                }
                vals[u] = v;
                m = fmaxf(m, v);
            }
            m = wave_max(m);
            if (lane == 0) sh.s4.sb[wid] = m;
            __syncthreads();
            if (tid == 0) sh.s4.sM = fmaxf(fmaxf(sh.s4.sb[0], sh.s4.sb[1]),
                                           fmaxf(sh.s4.sb[2], sh.s4.sb[3]));
            __syncthreads();
            m = sh.s4.sM;
            float s = 0.f;
            for (int u = 0; u < nu; ++u) s += expf(vals[u] - m);   // -inf -> 0
            __syncthreads();
            s = wave_sum(s);
            if (lane == 0) sh.s4.sb[wid] = s;
            __syncthreads();
            if (tid == 0) {
                float rl = m + logf(sh.s4.sb[0] + sh.s4.sb[1] + sh.s4.sb[2] + sh.s4.sb[3])
                           - sh.s4.sLabVal;
                atomicAdd(p.lsum, rl);
                __threadfence();
                int old = atomicAdd(p.lcnt, 1);
                if (old == p.Nn - 1) {
                    __threadfence();
                    float totl = atomicAdd(p.lsum, 0.f);   // coherent read via RMW
                    stv(p.out, 0, totl / (float)p.Nn, f32m);
                }
            }
        }
    }
}

// ===================== fallback 4-kernel path (R2, verbatim) =====================

__global__ __launch_bounds__(1024) void sort_prep(
        const int* __restrict__ labels, int* __restrict__ counts,
        int* __restrict__ offs, int* __restrict__ rows, int Nn, int C,
        const void* __restrict__ feat, unsigned short* __restrict__ featb, int total,
        float* __restrict__ lsum, int* __restrict__ lcnt) {
    __shared__ int h[1024];
    __shared__ int o[1024];
    __shared__ int cu[1024];
    int tid = threadIdx.x;
    if (blockIdx.x == 0) {
        h[tid] = 0;
        __syncthreads();
        for (int i = tid; i < Nn; i += 1024) atomicAdd(&h[labels[i]], 1);
        __syncthreads();
        o[tid] = h[tid];
        __syncthreads();
        for (int d = 1; d < 1024; d <<= 1) {
            int v = (tid >= d) ? o[tid - d] : 0;
            __syncthreads();
            o[tid] += v;
            __syncthreads();
        }
        int excl = o[tid] - h[tid];
        counts[tid] = h[tid];
        offs[tid] = excl;
        cu[tid] = excl;
        __syncthreads();
        for (int i = tid; i < Nn; i += 1024) {
            int pos = atomicAdd(&cu[labels[i]], 1);
            rows[pos] = i;
        }
        if (tid == 0) { *lsum = 0.f; *lcnt = 0; }
    } else {
        int f32m = block_sniff(feat);
        int i = ((blockIdx.x - 1) * 1024 + tid) * 8;
        if (i >= total) return;
        if (f32m) {
            const float* f = (const float*)feat + i;
            unsigned short r[8];
            #pragma unroll
            for (int u = 0; u < 8; ++u) r[u] = f2bu(f[u]);
            *(v8s*)(featb + i) = *(v8s*)r;
        } else {
            *(v8s*)(featb + i) = *(const v8s*)((const unsigned short*)feat + i);
        }
    }
}

__global__ __launch_bounds__(256) void finalize_stats(
        const unsigned short* __restrict__ featb,
        const int* __restrict__ counts, const int* __restrict__ offs,
        const int* __restrict__ rows,
        const void* __restrict__ ave, const void* __restrict__ cov,
        const void* __restrict__ amount, const void* __restrict__ W,
        const void* __restrict__ feat,
        void* __restrict__ out, size_t off_ave, size_t off_cov, size_t off_amt,
        unsigned short* __restrict__ Wb, unsigned short* __restrict__ W2b,
        unsigned short* __restrict__ Cb, unsigned short* __restrict__ Gb,
        float* __restrict__ T3p, int A, int A8) {
    __shared__ float sb[4];
    int f32m = block_sniff(feat);
    int c = blockIdx.y;
    int a = (blockIdx.x * 256 + threadIdx.x) * 2;
    size_t idx = (size_t)c * A + a;
    int cnti = counts[c];
    int start = offs[c];
    float s1[2] = {0.f, 0.f}, s2[2] = {0.f, 0.f};
    for (int i = 0; i < cnti; ++i) {
        unsigned u = *(const unsigned*)(featb + (size_t)rows[start + i] * A + a);
        float x0 = bu2f((unsigned short)(u & 0xffffu));
        float x1 = bu2f((unsigned short)(u >> 16));
        s1[0] += x0; s2[0] += x0 * x0;
        s1[1] += x1; s2[1] += x1 * x1;
    }
    float cnt = (float)cnti;
    float denom = cnti > 0 ? cnt : 1.f;
    float amt = ldv(amount, c, f32m);
    float tot = cnt + amt;
    float w = tot > 0.f ? (cnt / tot) : 0.f;
    float av[2], cv[2], wv[2];
    ld2(ave, idx, f32m, av);
    ld2(cov, idx, f32m, cv);
    ld2(W, idx, f32m, wv);
    unsigned short cb2[2], gb2[2];
    float t3s = 0.f;
    #pragma unroll
    for (int k = 0; k < 2; ++k) {
        float mean = s1[k] / denom;
        float var = fmaxf((s2[k] - cnt * mean * mean) / denom, 0.f);
        float d = av[k] - mean;
        float ncv = cv[k] * (1.f - w) + var * w + w * (1.f - w) * d * d;
        float nav = av[k] * (1.f - w) + mean * w;
        stv(out, off_cov + idx + k, ncv, f32m);
        stv(out, off_ave + idx + k, nav, f32m);
        cb2[k] = f2bu(ncv);
        gb2[k] = f2bu(ncv * wv[k]);
        t3s += wv[k] * wv[k] * ncv;
    }
    *(unsigned*)(Wb + idx)  = (unsigned)f2bu(wv[0]) | ((unsigned)f2bu(wv[1]) << 16);
    *(unsigned*)(W2b + idx) = (unsigned)f2bu(wv[0] * wv[0]) | ((unsigned)f2bu(wv[1] * wv[1]) << 16);
    *(unsigned*)(Cb + idx)  = (unsigned)cb2[0] | ((unsigned)cb2[1] << 16);
    *(unsigned*)(Gb + idx)  = (unsigned)gb2[0] | ((unsigned)gb2[1] << 16);
    if (a == 0) stv(out, off_amt + c, amt + cnt, f32m);
    float s = wave_sum(t3s);
    int lane = threadIdx.x & 63, wid = threadIdx.x >> 6;
    if (lane == 0) sb[wid] = s;
    __syncthreads();
    if (threadIdx.x == 0) T3p[(size_t)c * A8 + blockIdx.x] = sb[0] + sb[1] + sb[2] + sb[3];
}

__global__ __launch_bounds__(256) void triple_gemm_mfma(
        const unsigned short* __restrict__ featb,
        const unsigned short* __restrict__ Wb,
        const unsigned short* __restrict__ W2b,
        const unsigned short* __restrict__ Cb,
        const unsigned short* __restrict__ Gb,
        const int* __restrict__ labels,
        float* __restrict__ partY, float* __restrict__ partT1, float* __restrict__ partT2,
        int Cpad, int A, size_t NC) {
    __shared__ unsigned short sA[3][10240];
    __shared__ int sLab[64];
    int tid = threadIdx.x, wv = tid >> 6, lane = tid & 63;
    int n0 = blockIdx.y * 64, j0 = blockIdx.x * 64;
    int kslice = A / KSPLIT;
    int k0 = blockIdx.z * kslice;
    if (tid < 64) sLab[tid] = labels[n0 + tid];
    __syncthreads();

    int r = lane & 15, q = lane >> 4;
    int fr = wv * 16 + r;
    const unsigned short* pF = featb + (size_t)(n0 + fr) * A + k0 + q * 8;
    int lab = sLab[fr];
    const unsigned short* pC = Cb + (size_t)lab * A + k0 + q * 8;
    const unsigned short* pG = Gb + (size_t)lab * A + k0 + q * 8;
    const unsigned short* pW = Wb + (size_t)(j0 + fr) * A + k0 + q * 8;
    const unsigned short* pQ = W2b + (size_t)(j0 + fr) * A + k0 + q * 8;

    v4f aY[4] = {{0,0,0,0},{0,0,0,0},{0,0,0,0},{0,0,0,0}};
    v4f aT1[4] = {{0,0,0,0},{0,0,0,0},{0,0,0,0},{0,0,0,0}};
    v4f aT2[4] = {{0,0,0,0},{0,0,0,0},{0,0,0,0},{0,0,0,0}};

    const int NIT = kslice / 32;

    #define STAGE(b) do { \
        ld16(&sA[b][0    + wv * 512], pF); \
        ld16(&sA[b][2048 + wv * 512], pC); \
        ld16(&sA[b][4096 + wv * 512], pG); \
        ld16(&sA[b][6144 + wv * 512], pW); \
        ld16(&sA[b][8192 + wv * 512], pQ); \
        pF += 32; pC += 32; pG += 32; pW += 32; pQ += 32; } while (0)

    STAGE(0);
    STAGE(1);

    for (int it = 0; it < NIT; ++it) {
        int bcur = it % 3;
        if (it + 1 < NIT) asm volatile("s_waitcnt vmcnt(5)\n\ts_barrier" ::: "memory");
        else              asm volatile("s_waitcnt vmcnt(0)\n\ts_barrier" ::: "memory");
        if (it + 2 < NIT) { int bn = (it + 2) % 3; STAGE(bn); }
        v8s f = *(v8s*)&sA[bcur][0    + wv * 512 + lane * 8];
        v8s c = *(v8s*)&sA[bcur][2048 + wv * 512 + lane * 8];
        v8s g = *(v8s*)&sA[bcur][4096 + wv * 512 + lane * 8];
        #pragma unroll
        for (int t = 0; t < 4; ++t) {
            v8s w  = *(v8s*)&sA[bcur][6144 + t * 512 + lane * 8];
            v8s w2 = *(v8s*)&sA[bcur][8192 + t * 512 + lane * 8];
            aY[t]  = __builtin_amdgcn_mfma_f32_16x16x32_bf16(f, w,  aY[t],  0, 0, 0);
            aT1[t] = __builtin_amdgcn_mfma_f32_16x16x32_bf16(c, w2, aT1[t], 0, 0, 0);
            aT2[t] = __builtin_amdgcn_mfma_f32_16x16x32_bf16(g, w,  aT2[t], 0, 0, 0);
        }
    }
    #undef STAGE

    float* pY = partY + (size_t)blockIdx.z * NC;
    float* p1 = partT1 + (size_t)blockIdx.z * NC;
    float* p2 = partT2 + (size_t)blockIdx.z * NC;
    int quad = lane >> 4, colb = lane & 15;
    #pragma unroll
    for (int t = 0; t < 4; ++t) {
        int j = j0 + t * 16 + colb;
        #pragma unroll
        for (int rr = 0; rr < 4; ++rr) {
            int n = n0 + wv * 16 + quad * 4 + rr;
            size_t idx = (size_t)n * Cpad + j;
            pY[idx] = aY[t][rr];
            p1[idx] = aT1[t][rr];
            p2[idx] = aT2[t][rr];
        }
    }
}

__global__ __launch_bounds__(256) void epilogue_rowloss(
        const float* __restrict__ partY, const float* __restrict__ partT1,
        const float* __restrict__ partT2, const float* __restrict__ T3p,
        const void* __restrict__ bias, const void* __restrict__ feat,
        const int* __restrict__ labels,
        void* __restrict__ out, size_t off_y,
        float* __restrict__ lsum, int* __restrict__ lcnt,
        int C, int Cpad, int A8, const void* ratio_p, size_t NC, int Nn) {
    __shared__ float sb[4];
    __shared__ float sM;
    __shared__ float sLabVal;
    int f32m = block_sniff(feat);
    int tid = threadIdx.x;
    int n = blockIdx.x;
    int lab = labels[n];
    float t3 = 0.f;
    for (int i = 0; i < A8; ++i) t3 += T3p[(size_t)lab * A8 + i];
    float ratio = decode_scalar(ratio_p);

    float vals[8];
    int nu = Cpad >> 8;
    float m = -3.4e38f;
    for (int u = 0; u < nu; ++u) {
        int j = u * 256 + tid;
        float v = -3.4e38f;
        if (j < C) {
            size_t idx = (size_t)n * Cpad + j;
            float y = 0.f, t1 = 0.f, t2 = 0.f;
            #pragma unroll
            for (int z = 0; z < KSPLIT; ++z) {
                y  += partY[z * NC + idx];
                t1 += partT1[z * NC + idx];
                t2 += partT2[z * NC + idx];
            }
            y += ldv(bias, j, f32m);
            stv(out, off_y + (size_t)n * C + j, y, f32m);
            v = y + 0.5f * ratio * (t1 - 2.f * t2 + t3);
            if (j == lab) sLabVal = v;
        }
        vals[u] = v;
        m = fmaxf(m, v);
    }
    m = wave_max(m);
    int lane = tid & 63, wid = tid >> 6;
    if (lane == 0) sb[wid] = m;
    __syncthreads();
    if (tid == 0) sM = fmaxf(fmaxf(sb[0], sb[1]), fmaxf(sb[2], sb[3]));
    __syncthreads();
    m = sM;
    float s = 0.f;
    for (int u = 0; u < nu; ++u) s += expf(vals[u] - m);
    __syncthreads();
    s = wave_sum(s);
    if (lane == 0) sb[wid] = s;
    __syncthreads();
    if (tid == 0) {
        float rl = m + logf(sb[0] + sb[1] + sb[2] + sb[3]) - sLabVal;
        atomicAdd(lsum, rl);
        __threadfence();
        int old = atomicAdd(lcnt, 1);
        if (old == Nn - 1) {
            __threadfence();
            float total = atomicAdd(lsum, 0.f);
            stv(out, 0, total / (float)Nn, f32m);
        }
    }
}

extern "C" void kernel_launch(void* const* d_in, const int* in_sizes, int n_in,
                              void* d_out, int out_size, void* d_ws, size_t ws_size,
                              hipStream_t stream) {
    const void* feat   = d_in[0];
    const int*  labels = (const int*)d_in[1];
    const void* W      = d_in[2];
    const void* bias   = d_in[3];
    const void* ave    = d_in[4];
    const void* cov    = d_in[5];
    const void* amount = d_in[6];
    const void* ratiop = d_in[7];

    int NA = in_sizes[0];                  // N*A
    int Nn = in_sizes[1];                  // 512
    int C  = in_sizes[3];                  // 1000
    int A  = NA / Nn;                      // 2048
    int CA = in_sizes[2];                  // C*A
    int Cpad = ((C + 255) / 256) * 256;    // 1024
    int A8 = A / 512;                      // T3 chunks per class (512 cols/chunk)
    size_t NC = (size_t)Nn * Cpad;

    size_t off_y   = 1;
    size_t off_ave = off_y + (size_t)Nn * C;
    size_t off_cov = off_ave + (size_t)CA;
    size_t off_amt = off_cov + (size_t)CA;

    char* ws = (char*)d_ws;
    int*   w_cnt  = (int*)ws;                          // 1024
    int*   w_off  = w_cnt + 1024;                      // 1024
    int*   w_rows = w_off + 1024;                      // 1024
    float* w_T3p  = (float*)(w_rows + 1024);           // C*A8 (<= 8192)
    float* w_lsum = w_T3p + 8192;                      // 1 (region reserves 1024)
    int*   w_lcnt = (int*)(w_lsum + 1);                // 1
    float* w_partY  = w_lsum + 1024;                   // KSPLIT*NC
    float* w_partT1 = w_partY + KSPLIT * NC;           // KSPLIT*NC
    float* w_partT2 = w_partT1 + KSPLIT * NC;          // KSPLIT*NC
    unsigned short* w_featb = (unsigned short*)(w_partT2 + KSPLIT * NC);  // NA
    unsigned short* w_Wb    = w_featb + NA;            // CA
    unsigned short* w_W2b   = w_Wb + CA;               // CA
    unsigned short* w_Cb    = w_W2b + CA;              // CA
    unsigned short* w_Gb    = w_Cb + CA;               // CA

    // -------- preferred path: single cooperative mega-kernel --------
    bool coop_ok = (C <= 1024) && ((A & 511) == 0) && ((Nn & 63) == 0) &&
                   ((Cpad & 63) == 0) && (NA % 2048 == 0);
    if (coop_ok) {
        MegaArgs ma;
        ma.feat = feat; ma.labels = labels; ma.W = W; ma.bias = bias;
        ma.ave = ave; ma.cov = cov; ma.amount = amount; ma.ratiop = ratiop;
        ma.out = d_out;
        ma.off_y = off_y; ma.off_ave = off_ave; ma.off_cov = off_cov; ma.off_amt = off_amt;
        ma.counts = w_cnt; ma.offs = w_off; ma.rowsg = w_rows; ma.T3p = w_T3p;
        ma.lsum = w_lsum; ma.lcnt = w_lcnt;
        ma.partY = w_partY; ma.partT1 = w_partT1; ma.partT2 = w_partT2;
        ma.featb = w_featb; ma.Wb = w_Wb; ma.W2b = w_W2b; ma.Cb = w_Cb; ma.Gb = w_Gb;
        ma.Nn = Nn; ma.C = C; ma.A = A; ma.Cpad = Cpad; ma.A8 = A8;
        ma.total = NA; ma.NC = NC;
        void* kargs[] = { &ma };
        hipError_t e = hipLaunchCooperativeKernel((void*)isda_mega, dim3(512), dim3(256),
                                                  kargs, 0, stream);
        if (e == hipSuccess) return;
        (void)hipGetLastError();   // clear sticky error; fall through to 4-kernel path
    }

    // -------- fallback: R2 4-kernel path --------
    int prep_blocks = NA / 8192;
    sort_prep<<<1 + prep_blocks, 1024, 0, stream>>>(
        labels, w_cnt, w_off, w_rows, Nn, C, feat, w_featb, NA, w_lsum, w_lcnt);
    dim3 g2(A / 512, C);
    finalize_stats<<<g2, 256, 0, stream>>>(w_featb, w_cnt, w_off, w_rows,
                                           ave, cov, amount, W, feat,
                                           d_out, off_ave, off_cov, off_amt,
                                           w_Wb, w_W2b, w_Cb, w_Gb, w_T3p, A, A8);
    dim3 g3(Cpad / 64, Nn / 64, KSPLIT);
    triple_gemm_mfma<<<g3, 256, 0, stream>>>(w_featb, w_Wb, w_W2b, w_Cb, w_Gb,
                                             labels, w_partY, w_partT1, w_partT2,
                                             Cpad, A, NC);
    epilogue_rowloss<<<Nn, 256, 0, stream>>>(w_partY, w_partT1, w_partT2, w_T3p,
                                             bias, feat, labels, d_out, off_y,
                                             w_lsum, w_lcnt,
                                             C, Cpad, A8, ratiop, NC, Nn);
}

// Round 4
// 143.101 us; speedup vs baseline: 3.4707x; 3.4707x over previous
//
#include <hip/hip_runtime.h>
#include <hip/hip_bf16.h>

typedef short v8s __attribute__((ext_vector_type(8)));
typedef float v4f __attribute__((ext_vector_type(4)));

#define KSPLIT 4

// ---- dual-dtype element access (f32m: 0 = bf16, 1 = f32) ----
static __device__ __forceinline__ float ldv(const void* p, size_t i, int f32m) {
    if (f32m) return ((const float*)p)[i];
    return __bfloat162float(((const __hip_bfloat16*)p)[i]);
}
static __device__ __forceinline__ void stv(void* p, size_t i, float v, int f32m) {
    if (f32m) ((float*)p)[i] = v;
    else ((__hip_bfloat16*)p)[i] = __float2bfloat16(v);
}
static __device__ __forceinline__ unsigned short f2bu(float x) {
    __hip_bfloat16 h = __float2bfloat16(x);
    return *(unsigned short*)&h;
}
static __device__ __forceinline__ float bu2f(unsigned short u) {
    return __uint_as_float(((unsigned)u) << 16);
}
// paired (2-element) load: f32 -> float2, bf16 -> ushort2
static __device__ __forceinline__ void ld2(const void* p, size_t i, int f32m, float* o) {
    if (f32m) {
        float2 v = *(const float2*)((const float*)p + i);
        o[0] = v.x; o[1] = v.y;
    } else {
        unsigned u = *(const unsigned*)((const unsigned short*)p + i);
        o[0] = bu2f((unsigned short)(u & 0xffffu));
        o[1] = bu2f((unsigned short)(u >> 16));
    }
}

// Robust scalar decode: handles int32, float32, or bf16-in-low-16 encodings.
static __device__ __forceinline__ float decode_scalar(const void* p) {
    unsigned u = *(const unsigned*)p;
    unsigned e32 = (u >> 23) & 0xff;
    if (e32 >= 97 && e32 <= 160) return __uint_as_float(u);
    unsigned lo = u & 0xffffu;
    unsigned e16 = (lo >> 7) & 0xff;
    if ((u >> 16) == 0 && e16 >= 97 && e16 <= 160)
        return __uint_as_float(lo << 16);
    return (float)(int)u;
}

// Per-block dtype sniff (deterministic; contains a barrier — call unconditionally
// on a block-uniform path before any other barrier use).
static __device__ __forceinline__ int block_sniff(const void* feat) {
    const __hip_bfloat16* p = (const __hip_bfloat16*)feat;
    float v = __bfloat162float(p[threadIdx.x & 255]);
    int bad = !(fabsf(v) < 1e10f);
    return __syncthreads_or(bad) ? 1 : 0;
}

__device__ __forceinline__ float wave_sum(float v) {
    #pragma unroll
    for (int o = 32; o > 0; o >>= 1) v += __shfl_down(v, o, 64);
    return v;
}
__device__ __forceinline__ float wave_max(float v) {
    #pragma unroll
    for (int o = 32; o > 0; o >>= 1) v = fmaxf(v, __shfl_down(v, o, 64));
    return v;
}

// async global->LDS, 16B per lane, LDS dst = wave-uniform base + lane*16
static __device__ __forceinline__ void ld16(unsigned short* lds, const unsigned short* g) {
    __builtin_amdgcn_global_load_lds(
        (const __attribute__((address_space(1))) unsigned int*)g,
        (__attribute__((address_space(3))) unsigned int*)lds,
        16, 0, 0);
}

// K1: fused stats + prep. Block = (class c = blockIdx.y, 512-col chunk = blockIdx.x).
//  (a) side-job: grid-strided feat -> bf16 featb conversion (f32 mode only;
//      in bf16 mode the GEMM reads feat directly)
//  (b) per-block label scan (no global sort): LDS row list for class c
//  (c) mean/var gather DIRECTLY from feat, then new_ave/new_cov/new_amount,
//      bf16 GEMM operands (Gb pre-scaled by -2), T3 partials.
__global__ __launch_bounds__(256) void stats_prep(
        const void* __restrict__ feat, const int* __restrict__ labels,
        const void* __restrict__ ave, const void* __restrict__ cov,
        const void* __restrict__ amount, const void* __restrict__ W,
        void* __restrict__ out, size_t off_ave, size_t off_cov, size_t off_amt,
        unsigned short* __restrict__ featb,
        unsigned short* __restrict__ Wb, unsigned short* __restrict__ W2b,
        unsigned short* __restrict__ Cb, unsigned short* __restrict__ Gb,
        float* __restrict__ T3p, float* __restrict__ lsum, int* __restrict__ lcnt,
        int Nn, int A, int A8, int NA) {
    __shared__ int sRows[2048];
    __shared__ int sCnt;
    __shared__ float sb[4];
    int tid = threadIdx.x;
    int f32m = block_sniff(feat);

    // (a) conversion side-job (each block converts one 2048-elem chunk, striped)
    if (f32m) {
        int flat = blockIdx.y * gridDim.x + blockIdx.x;
        int nblk = gridDim.x * gridDim.y;
        for (long long i = ((long long)flat * 256 + tid) * 8; i < NA;
             i += (long long)nblk * 2048) {
            const float* f = (const float*)feat + i;
            unsigned short r8[8];
            #pragma unroll
            for (int u = 0; u < 8; ++u) r8[u] = f2bu(f[u]);
            *(v8s*)(featb + i) = *(v8s*)r8;
        }
    }
    if (blockIdx.x == 0 && blockIdx.y == 0 && tid == 0) { *lsum = 0.f; *lcnt = 0; }

    // (b)+(c) stats for this (class, column-chunk)
    int c = blockIdx.y;
    int a = (blockIdx.x * 256 + tid) * 2;
    size_t idx = (size_t)c * A + a;
    float s1v[2] = {0.f, 0.f}, s2v[2] = {0.f, 0.f};
    int cnti = 0;
    for (int base = 0; base < Nn; base += 2048) {
        int lim = min(Nn - base, 2048);
        if (tid == 0) sCnt = 0;
        __syncthreads();
        for (int i = tid; i < lim; i += 256)
            if (labels[base + i] == c) { int pp = atomicAdd(&sCnt, 1); sRows[pp] = base + i; }
        __syncthreads();
        int cl = sCnt;
        cnti += cl;
        for (int i = 0; i < cl; ++i) {
            float x[2];
            ld2(feat, (size_t)sRows[i] * A + a, f32m, x);
            s1v[0] += x[0]; s2v[0] += x[0] * x[0];
            s1v[1] += x[1]; s2v[1] += x[1] * x[1];
        }
        __syncthreads();   // protect sCnt/sRows reuse next chunk
    }
    float cnt = (float)cnti;
    float denomv = cnti > 0 ? cnt : 1.f;
    float amt = ldv(amount, c, f32m);
    float tot = cnt + amt;
    float w = tot > 0.f ? (cnt / tot) : 0.f;   // nan_to_num(0/0) -> 0
    float av[2], cvv[2], wvv[2];
    ld2(ave, idx, f32m, av);
    ld2(cov, idx, f32m, cvv);
    ld2(W, idx, f32m, wvv);
    unsigned short cb2[2], gb2[2];
    float t3s = 0.f;
    #pragma unroll
    for (int k = 0; k < 2; ++k) {
        float mean = s1v[k] / denomv;
        float var = fmaxf((s2v[k] - cnt * mean * mean) / denomv, 0.f);
        float d = av[k] - mean;
        float ncv = cvv[k] * (1.f - w) + var * w + w * (1.f - w) * d * d;
        float nav = av[k] * (1.f - w) + mean * w;
        stv(out, off_cov + idx + k, ncv, f32m);
        stv(out, off_ave + idx + k, nav, f32m);
        cb2[k] = f2bu(ncv);
        gb2[k] = f2bu(-2.f * ncv * wvv[k]);    // -2 baked in: sigma GEMM fuses t1-2*t2
        t3s += wvv[k] * wvv[k] * ncv;
    }
    *(unsigned*)(Wb + idx)  = (unsigned)f2bu(wvv[0]) | ((unsigned)f2bu(wvv[1]) << 16);
    *(unsigned*)(W2b + idx) = (unsigned)f2bu(wvv[0] * wvv[0]) | ((unsigned)f2bu(wvv[1] * wvv[1]) << 16);
    *(unsigned*)(Cb + idx)  = (unsigned)cb2[0] | ((unsigned)cb2[1] << 16);
    *(unsigned*)(Gb + idx)  = (unsigned)gb2[0] | ((unsigned)gb2[1] << 16);
    if (a == 0) stv(out, off_amt + c, amt + cnt, f32m);
    // T3 partial for this (c, chunk): sum of W^2 * ncov
    float s = wave_sum(t3s);
    int lane = tid & 63, wid = tid >> 6;
    if (lane == 0) sb[wid] = s;
    __syncthreads();
    if (tid == 0) T3p[(size_t)c * A8 + blockIdx.x] = sb[0] + sb[1] + sb[2] + sb[3];
}

// K2: split-K fused MFMA dual-accumulator GEMM -> per-slice partials.
// Y = F*W^T ; S = C*W2^T + G*W^T (G pre-scaled -2 => S = t1 - 2*t2).
// Triple-buffered LDS, counted-vmcnt pipeline (R2-proven): wait only the oldest
// stage's 5 DMAs (vmcnt(5)) before the barrier, keep the next stage in flight.
__global__ __launch_bounds__(256) void triple_gemm_mfma(
        const void* __restrict__ feat,
        const unsigned short* __restrict__ featb,
        const unsigned short* __restrict__ Wb,
        const unsigned short* __restrict__ W2b,
        const unsigned short* __restrict__ Cb,
        const unsigned short* __restrict__ Gb,
        const int* __restrict__ labels,
        float* __restrict__ partY, float* __restrict__ partS,
        int Cpad, int A, size_t NC) {
    __shared__ unsigned short sA[3][10240];   // per buf: F:0 C:2048 G:4096 W:6144 W2:8192
    __shared__ int sLab[64];
    int tid = threadIdx.x, wv = tid >> 6, lane = tid & 63;
    int f32m = block_sniff(feat);
    const unsigned short* Fsrc = f32m ? featb : (const unsigned short*)feat;
    int n0 = blockIdx.y * 64, j0 = blockIdx.x * 64;
    int kslice = A / KSPLIT;
    int k0 = blockIdx.z * kslice;
    if (tid < 64) sLab[tid] = labels[n0 + tid];
    __syncthreads();

    int r = lane & 15, q = lane >> 4;
    int fr = wv * 16 + r;
    const unsigned short* pF = Fsrc + (size_t)(n0 + fr) * A + k0 + q * 8;
    int lab = sLab[fr];
    const unsigned short* pC = Cb + (size_t)lab * A + k0 + q * 8;
    const unsigned short* pG = Gb + (size_t)lab * A + k0 + q * 8;
    const unsigned short* pW = Wb + (size_t)(j0 + fr) * A + k0 + q * 8;
    const unsigned short* pQ = W2b + (size_t)(j0 + fr) * A + k0 + q * 8;

    v4f aY[4] = {{0,0,0,0},{0,0,0,0},{0,0,0,0},{0,0,0,0}};
    v4f aS[4] = {{0,0,0,0},{0,0,0,0},{0,0,0,0},{0,0,0,0}};

    const int NIT = kslice / 32;   // 16 at A=2048, KSPLIT=4

    #define STAGE(b) do { \
        ld16(&sA[b][0    + wv * 512], pF); \
        ld16(&sA[b][2048 + wv * 512], pC); \
        ld16(&sA[b][4096 + wv * 512], pG); \
        ld16(&sA[b][6144 + wv * 512], pW); \
        ld16(&sA[b][8192 + wv * 512], pQ); \
        pF += 32; pC += 32; pG += 32; pW += 32; pQ += 32; } while (0)

    STAGE(0);
    STAGE(1);

    for (int it = 0; it < NIT; ++it) {
        int bcur = it % 3;
        // outstanding here: stage(it) + stage(it+1) = 10 DMAs (5 on last iter)
        if (it + 1 < NIT) asm volatile("s_waitcnt vmcnt(5)\n\ts_barrier" ::: "memory");
        else              asm volatile("s_waitcnt vmcnt(0)\n\ts_barrier" ::: "memory");
        if (it + 2 < NIT) { int bn = (it + 2) % 3; STAGE(bn); }
        v8s f = *(v8s*)&sA[bcur][0    + wv * 512 + lane * 8];
        v8s c = *(v8s*)&sA[bcur][2048 + wv * 512 + lane * 8];
        v8s g = *(v8s*)&sA[bcur][4096 + wv * 512 + lane * 8];
        #pragma unroll
        for (int t = 0; t < 4; ++t) {
            v8s w  = *(v8s*)&sA[bcur][6144 + t * 512 + lane * 8];
            v8s w2 = *(v8s*)&sA[bcur][8192 + t * 512 + lane * 8];
            aY[t] = __builtin_amdgcn_mfma_f32_16x16x32_bf16(f, w,  aY[t], 0, 0, 0);
            aS[t] = __builtin_amdgcn_mfma_f32_16x16x32_bf16(c, w2, aS[t], 0, 0, 0);
            aS[t] = __builtin_amdgcn_mfma_f32_16x16x32_bf16(g, w,  aS[t], 0, 0, 0);
        }
    }
    #undef STAGE

    // C/D layout: col = lane&15, row = (lane>>4)*4 + reg.
    float* pY = partY + (size_t)blockIdx.z * NC;
    float* pS = partS + (size_t)blockIdx.z * NC;
    int quad = lane >> 4, colb = lane & 15;
    #pragma unroll
    for (int t = 0; t < 4; ++t) {
        int j = j0 + t * 16 + colb;
        #pragma unroll
        for (int rr = 0; rr < 4; ++rr) {
            int n = n0 + wv * 16 + quad * 4 + rr;
            size_t idx = (size_t)n * Cpad + j;
            pY[idx] = aY[t][rr];
            pS[idx] = aS[t][rr];
        }
    }
}

// K3: fused epilogue + row loss + mean. One block per row n: sum split-K
// partials, add bias, store y, isda logits in registers, logsumexp, then
// device-scope atomic accumulate of mean loss; last block writes out[0].
__global__ __launch_bounds__(256) void epilogue_rowloss(
        const float* __restrict__ partY, const float* __restrict__ partS,
        const float* __restrict__ T3p,
        const void* __restrict__ bias, const void* __restrict__ feat,
        const int* __restrict__ labels,
        void* __restrict__ out, size_t off_y,
        float* __restrict__ lsum, int* __restrict__ lcnt,
        int C, int Cpad, int A8, const void* ratio_p, size_t NC, int Nn) {
    __shared__ float sb[4];
    __shared__ float sM;
    __shared__ float sLabVal;
    int f32m = block_sniff(feat);
    int tid = threadIdx.x;
    int n = blockIdx.x;
    int lab = labels[n];
    float t3 = 0.f;
    for (int i = 0; i < A8; ++i) t3 += T3p[(size_t)lab * A8 + i];
    float ratio = decode_scalar(ratio_p);

    float vals[8];
    int nu = Cpad >> 8;        // <= 8 assumed (C <= 2048)
    float m = -3.4e38f;
    #pragma unroll
    for (int u = 0; u < 8; ++u) {     // static indexing: vals stays in registers
        float v = -3.4e38f;
        if (u < nu) {
            int j = u * 256 + tid;
            if (j < C) {
                size_t idx = (size_t)n * Cpad + j;
                float y = 0.f, s = 0.f;
                #pragma unroll
                for (int z = 0; z < KSPLIT; ++z) {
                    y += partY[z * NC + idx];
                    s += partS[z * NC + idx];
                }
                y += ldv(bias, j, f32m);
                stv(out, off_y + (size_t)n * C + j, y, f32m);
                v = y + 0.5f * ratio * (s + t3);
                if (j == lab) sLabVal = v;
            }
        }
        vals[u] = v;
        m = fmaxf(m, v);
    }
    // block max
    m = wave_max(m);
    int lane = tid & 63, wid = tid >> 6;
    if (lane == 0) sb[wid] = m;
    __syncthreads();
    if (tid == 0) sM = fmaxf(fmaxf(sb[0], sb[1]), fmaxf(sb[2], sb[3]));
    __syncthreads();
    m = sM;
    float s = 0.f;
    #pragma unroll
    for (int u = 0; u < 8; ++u) s += (u < nu) ? expf(vals[u] - m) : 0.f;   // -inf -> 0
    __syncthreads();
    s = wave_sum(s);
    if (lane == 0) sb[wid] = s;
    __syncthreads();
    if (tid == 0) {
        float rl = m + logf(sb[0] + sb[1] + sb[2] + sb[3]) - sLabVal;
        atomicAdd(lsum, rl);
        __threadfence();
        int old = atomicAdd(lcnt, 1);
        if (old == Nn - 1) {
            __threadfence();
            float total = atomicAdd(lsum, 0.f);   // coherent read via RMW
            stv(out, 0, total / (float)Nn, f32m);
        }
    }
}

extern "C" void kernel_launch(void* const* d_in, const int* in_sizes, int n_in,
                              void* d_out, int out_size, void* d_ws, size_t ws_size,
                              hipStream_t stream) {
    const void* feat   = d_in[0];
    const int*  labels = (const int*)d_in[1];
    const void* W      = d_in[2];
    const void* bias   = d_in[3];
    const void* ave    = d_in[4];
    const void* cov    = d_in[5];
    const void* amount = d_in[6];
    const void* ratiop = d_in[7];

    int NA = in_sizes[0];                  // N*A
    int Nn = in_sizes[1];                  // 512
    int C  = in_sizes[3];                  // 1000
    int A  = NA / Nn;                      // 2048
    int CA = in_sizes[2];                  // C*A
    int Cpad = ((C + 255) / 256) * 256;    // 1024
    int A8 = A / 512;                      // T3 chunks per class (512 cols/chunk)
    size_t NC = (size_t)Nn * Cpad;

    size_t off_y   = 1;
    size_t off_ave = off_y + (size_t)Nn * C;
    size_t off_cov = off_ave + (size_t)CA;
    size_t off_amt = off_cov + (size_t)CA;

    char* ws = (char*)d_ws;
    float* w_T3p  = (float*)ws;                        // C*A8 (<= 8192 floats reserved)
    float* w_lsum = w_T3p + 8192;                      // 1 (region reserves 1024)
    int*   w_lcnt = (int*)(w_lsum + 1);                // 1
    float* w_partY = w_lsum + 1024;                    // KSPLIT*NC
    float* w_partS = w_partY + KSPLIT * NC;            // KSPLIT*NC
    unsigned short* w_featb = (unsigned short*)(w_partS + KSPLIT * NC);   // NA
    unsigned short* w_Wb    = w_featb + NA;            // CA
    unsigned short* w_W2b   = w_Wb + CA;               // CA
    unsigned short* w_Cb    = w_W2b + CA;              // CA
    unsigned short* w_Gb    = w_Cb + CA;               // CA

    dim3 g1(A / 512, C);
    stats_prep<<<g1, 256, 0, stream>>>(feat, labels, ave, cov, amount, W,
                                       d_out, off_ave, off_cov, off_amt,
                                       w_featb, w_Wb, w_W2b, w_Cb, w_Gb,
                                       w_T3p, w_lsum, w_lcnt, Nn, A, A8, NA);
    dim3 g2(Cpad / 64, Nn / 64, KSPLIT);
    triple_gemm_mfma<<<g2, 256, 0, stream>>>(feat, w_featb, w_Wb, w_W2b, w_Cb, w_Gb,
                                             labels, w_partY, w_partS, Cpad, A, NC);
    epilogue_rowloss<<<Nn, 256, 0, stream>>>(w_partY, w_partS, w_T3p,
                                             bias, feat, labels, d_out, off_y,
                                             w_lsum, w_lcnt,
                                             C, Cpad, A8, ratiop, NC, Nn);
}

// Round 5
// 142.084 us; speedup vs baseline: 3.4955x; 1.0072x over previous
//
#include <hip/hip_runtime.h>
#include <hip/hip_bf16.h>

typedef short v8s __attribute__((ext_vector_type(8)));
typedef float v4f __attribute__((ext_vector_type(4)));

#define KSPLIT 4

// ---- dual-dtype element access (f32m: 0 = bf16, 1 = f32) ----
static __device__ __forceinline__ float ldv(const void* p, size_t i, int f32m) {
    if (f32m) return ((const float*)p)[i];
    return __bfloat162float(((const __hip_bfloat16*)p)[i]);
}
static __device__ __forceinline__ void stv(void* p, size_t i, float v, int f32m) {
    if (f32m) ((float*)p)[i] = v;
    else ((__hip_bfloat16*)p)[i] = __float2bfloat16(v);
}
static __device__ __forceinline__ unsigned short f2bu(float x) {
    __hip_bfloat16 h = __float2bfloat16(x);
    return *(unsigned short*)&h;
}
static __device__ __forceinline__ float bu2f(unsigned short u) {
    return __uint_as_float(((unsigned)u) << 16);
}
// paired (2-element) load: f32 -> float2, bf16 -> ushort2
static __device__ __forceinline__ void ld2(const void* p, size_t i, int f32m, float* o) {
    if (f32m) {
        float2 v = *(const float2*)((const float*)p + i);
        o[0] = v.x; o[1] = v.y;
    } else {
        unsigned u = *(const unsigned*)((const unsigned short*)p + i);
        o[0] = bu2f((unsigned short)(u & 0xffffu));
        o[1] = bu2f((unsigned short)(u >> 16));
    }
}

// Robust scalar decode: handles int32, float32, or bf16-in-low-16 encodings.
static __device__ __forceinline__ float decode_scalar(const void* p) {
    unsigned u = *(const unsigned*)p;
    unsigned e32 = (u >> 23) & 0xff;
    if (e32 >= 97 && e32 <= 160) return __uint_as_float(u);
    unsigned lo = u & 0xffffu;
    unsigned e16 = (lo >> 7) & 0xff;
    if ((u >> 16) == 0 && e16 >= 97 && e16 <= 160)
        return __uint_as_float(lo << 16);
    return (float)(int)u;
}

// Per-block dtype sniff (deterministic; contains a barrier — call unconditionally
// on a block-uniform path before any other barrier use).
static __device__ __forceinline__ int block_sniff(const void* feat) {
    const __hip_bfloat16* p = (const __hip_bfloat16*)feat;
    float v = __bfloat162float(p[threadIdx.x & 255]);
    int bad = !(fabsf(v) < 1e10f);
    return __syncthreads_or(bad) ? 1 : 0;
}

__device__ __forceinline__ float wave_sum(float v) {
    #pragma unroll
    for (int o = 32; o > 0; o >>= 1) v += __shfl_down(v, o, 64);
    return v;
}
__device__ __forceinline__ float wave_max(float v) {
    #pragma unroll
    for (int o = 32; o > 0; o >>= 1) v = fmaxf(v, __shfl_down(v, o, 64));
    return v;
}

// async global->LDS, 16B per lane, LDS dst = wave-uniform base + lane*16
static __device__ __forceinline__ void ld16(unsigned short* lds, const unsigned short* g) {
    __builtin_amdgcn_global_load_lds(
        (const __attribute__((address_space(1))) unsigned int*)g,
        (__attribute__((address_space(3))) unsigned int*)lds,
        16, 0, 0);
}

// K1: fused stats + prep. Block = (class c = blockIdx.y, 512-col chunk = blockIdx.x).
//  (a) side-job: grid-strided feat -> bf16 featb conversion (f32 mode only;
//      in bf16 mode the GEMM reads feat directly)
//  (b) per-block label scan (no global sort): LDS row list for class c
//  (c) mean/var gather DIRECTLY from feat, then new_ave/new_cov/new_amount,
//      bf16 GEMM operands (Gb pre-scaled by -2), T3 partials.
__global__ __launch_bounds__(256) void stats_prep(
        const void* __restrict__ feat, const int* __restrict__ labels,
        const void* __restrict__ ave, const void* __restrict__ cov,
        const void* __restrict__ amount, const void* __restrict__ W,
        void* __restrict__ out, size_t off_ave, size_t off_cov, size_t off_amt,
        unsigned short* __restrict__ featb,
        unsigned short* __restrict__ Wb, unsigned short* __restrict__ W2b,
        unsigned short* __restrict__ Cb, unsigned short* __restrict__ Gb,
        float* __restrict__ T3p, float* __restrict__ lsum, int* __restrict__ lcnt,
        int Nn, int A, int A8, int NA) {
    __shared__ int sRows[2048];
    __shared__ int sCnt;
    __shared__ float sb[4];
    int tid = threadIdx.x;
    int f32m = block_sniff(feat);

    // (a) conversion side-job (each block converts one 2048-elem chunk, striped)
    if (f32m) {
        int flat = blockIdx.y * gridDim.x + blockIdx.x;
        int nblk = gridDim.x * gridDim.y;
        for (long long i = ((long long)flat * 256 + tid) * 8; i < NA;
             i += (long long)nblk * 2048) {
            const float* f = (const float*)feat + i;
            unsigned short r8[8];
            #pragma unroll
            for (int u = 0; u < 8; ++u) r8[u] = f2bu(f[u]);
            *(v8s*)(featb + i) = *(v8s*)r8;
        }
    }
    if (blockIdx.x == 0 && blockIdx.y == 0 && tid == 0) { *lsum = 0.f; *lcnt = 0; }

    // (b)+(c) stats for this (class, column-chunk)
    int c = blockIdx.y;
    int a = (blockIdx.x * 256 + tid) * 2;
    size_t idx = (size_t)c * A + a;
    float s1v[2] = {0.f, 0.f}, s2v[2] = {0.f, 0.f};
    int cnti = 0;
    for (int base = 0; base < Nn; base += 2048) {
        int lim = min(Nn - base, 2048);
        if (tid == 0) sCnt = 0;
        __syncthreads();
        for (int i = tid; i < lim; i += 256)
            if (labels[base + i] == c) { int pp = atomicAdd(&sCnt, 1); sRows[pp] = base + i; }
        __syncthreads();
        int cl = sCnt;
        cnti += cl;
        for (int i = 0; i < cl; ++i) {
            float x[2];
            ld2(feat, (size_t)sRows[i] * A + a, f32m, x);
            s1v[0] += x[0]; s2v[0] += x[0] * x[0];
            s1v[1] += x[1]; s2v[1] += x[1] * x[1];
        }
        __syncthreads();   // protect sCnt/sRows reuse next chunk
    }
    float cnt = (float)cnti;
    float denomv = cnti > 0 ? cnt : 1.f;
    float amt = ldv(amount, c, f32m);
    float tot = cnt + amt;
    float w = tot > 0.f ? (cnt / tot) : 0.f;   // nan_to_num(0/0) -> 0
    float av[2], cvv[2], wvv[2];
    ld2(ave, idx, f32m, av);
    ld2(cov, idx, f32m, cvv);
    ld2(W, idx, f32m, wvv);
    unsigned short cb2[2], gb2[2];
    float t3s = 0.f;
    #pragma unroll
    for (int k = 0; k < 2; ++k) {
        float mean = s1v[k] / denomv;
        float var = fmaxf((s2v[k] - cnt * mean * mean) / denomv, 0.f);
        float d = av[k] - mean;
        float ncv = cvv[k] * (1.f - w) + var * w + w * (1.f - w) * d * d;
        float nav = av[k] * (1.f - w) + mean * w;
        stv(out, off_cov + idx + k, ncv, f32m);
        stv(out, off_ave + idx + k, nav, f32m);
        cb2[k] = f2bu(ncv);
        gb2[k] = f2bu(-2.f * ncv * wvv[k]);    // -2 baked in: sigma GEMM fuses t1-2*t2
        t3s += wvv[k] * wvv[k] * ncv;
    }
    *(unsigned*)(Wb + idx)  = (unsigned)f2bu(wvv[0]) | ((unsigned)f2bu(wvv[1]) << 16);
    *(unsigned*)(W2b + idx) = (unsigned)f2bu(wvv[0] * wvv[0]) | ((unsigned)f2bu(wvv[1] * wvv[1]) << 16);
    *(unsigned*)(Cb + idx)  = (unsigned)cb2[0] | ((unsigned)cb2[1] << 16);
    *(unsigned*)(Gb + idx)  = (unsigned)gb2[0] | ((unsigned)gb2[1] << 16);
    if (a == 0) stv(out, off_amt + c, amt + cnt, f32m);
    // T3 partial for this (c, chunk): sum of W^2 * ncov
    float s = wave_sum(t3s);
    int lane = tid & 63, wid = tid >> 6;
    if (lane == 0) sb[wid] = s;
    __syncthreads();
    if (tid == 0) T3p[(size_t)c * A8 + blockIdx.x] = sb[0] + sb[1] + sb[2] + sb[3];
}

// K2: split-K fused MFMA dual-accumulator GEMM -> per-slice partials.
// Y = F*W^T ; S = C*W2^T + G*W^T (G pre-scaled -2 => S = t1 - 2*t2).
// Triple-buffered LDS, counted-vmcnt pipeline (R2-proven).
// SWZ=1: flat 512-block launch with CHUNKED XCD mapping — each XCD owns one
// z-slice x 4 row-panels x all 16 col-tiles, so its staged working set
// (~2.8 MB: F/C/G for 4 row-panels + W/W2 for 16 col-panels) fits its
// private 4 MB L2. Default round-robin dispatch (stride-1 = alternating XCD)
// re-fetches row-panels through L3 up to 16x.
template<int SWZ>
__global__ __launch_bounds__(256) void triple_gemm_mfma(
        const void* __restrict__ feat,
        const unsigned short* __restrict__ featb,
        const unsigned short* __restrict__ Wb,
        const unsigned short* __restrict__ W2b,
        const unsigned short* __restrict__ Cb,
        const unsigned short* __restrict__ Gb,
        const int* __restrict__ labels,
        float* __restrict__ partY, float* __restrict__ partS,
        int Cpad, int A, size_t NC) {
    __shared__ unsigned short sA[3][10240];   // per buf: F:0 C:2048 G:4096 W:6144 W2:8192
    __shared__ int sLab[64];
    int tid = threadIdx.x, wv = tid >> 6, lane = tid & 63;
    int f32m = block_sniff(feat);
    const unsigned short* Fsrc = f32m ? featb : (const unsigned short*)feat;

    int bx, by, bz;
    if (SWZ) {
        // 512 blocks, 8 XCDs, 64 blocks/XCD (all co-resident at 2 blocks/CU).
        // vid = chunked remap; decode assumes gx=16, gy=8, gz=4 (guarded at launch).
        int bid = blockIdx.x;
        int vid = (bid & 7) * 64 + (bid >> 3);
        bx = vid & 15; by = (vid >> 4) & 7; bz = vid >> 7;
    } else {
        bx = blockIdx.x; by = blockIdx.y; bz = blockIdx.z;
    }

    int n0 = by * 64, j0 = bx * 64;
    int kslice = A / KSPLIT;
    int k0 = bz * kslice;
    if (tid < 64) sLab[tid] = labels[n0 + tid];
    __syncthreads();

    int r = lane & 15, q = lane >> 4;
    int fr = wv * 16 + r;
    const unsigned short* pF = Fsrc + (size_t)(n0 + fr) * A + k0 + q * 8;
    int lab = sLab[fr];
    const unsigned short* pC = Cb + (size_t)lab * A + k0 + q * 8;
    const unsigned short* pG = Gb + (size_t)lab * A + k0 + q * 8;
    const unsigned short* pW = Wb + (size_t)(j0 + fr) * A + k0 + q * 8;
    const unsigned short* pQ = W2b + (size_t)(j0 + fr) * A + k0 + q * 8;

    v4f aY[4] = {{0,0,0,0},{0,0,0,0},{0,0,0,0},{0,0,0,0}};
    v4f aS[4] = {{0,0,0,0},{0,0,0,0},{0,0,0,0},{0,0,0,0}};

    const int NIT = kslice / 32;   // 16 at A=2048, KSPLIT=4

    #define STAGE(b) do { \
        ld16(&sA[b][0    + wv * 512], pF); \
        ld16(&sA[b][2048 + wv * 512], pC); \
        ld16(&sA[b][4096 + wv * 512], pG); \
        ld16(&sA[b][6144 + wv * 512], pW); \
        ld16(&sA[b][8192 + wv * 512], pQ); \
        pF += 32; pC += 32; pG += 32; pW += 32; pQ += 32; } while (0)

    STAGE(0);
    STAGE(1);

    for (int it = 0; it < NIT; ++it) {
        int bcur = it % 3;
        // outstanding here: stage(it) + stage(it+1) = 10 DMAs (5 on last iter)
        if (it + 1 < NIT) asm volatile("s_waitcnt vmcnt(5)\n\ts_barrier" ::: "memory");
        else              asm volatile("s_waitcnt vmcnt(0)\n\ts_barrier" ::: "memory");
        if (it + 2 < NIT) { int bn = (it + 2) % 3; STAGE(bn); }
        v8s f = *(v8s*)&sA[bcur][0    + wv * 512 + lane * 8];
        v8s c = *(v8s*)&sA[bcur][2048 + wv * 512 + lane * 8];
        v8s g = *(v8s*)&sA[bcur][4096 + wv * 512 + lane * 8];
        #pragma unroll
        for (int t = 0; t < 4; ++t) {
            v8s w  = *(v8s*)&sA[bcur][6144 + t * 512 + lane * 8];
            v8s w2 = *(v8s*)&sA[bcur][8192 + t * 512 + lane * 8];
            aY[t] = __builtin_amdgcn_mfma_f32_16x16x32_bf16(f, w,  aY[t], 0, 0, 0);
            aS[t] = __builtin_amdgcn_mfma_f32_16x16x32_bf16(c, w2, aS[t], 0, 0, 0);
            aS[t] = __builtin_amdgcn_mfma_f32_16x16x32_bf16(g, w,  aS[t], 0, 0, 0);
        }
    }
    #undef STAGE

    // C/D layout: col = lane&15, row = (lane>>4)*4 + reg.
    float* pY = partY + (size_t)bz * NC;
    float* pS = partS + (size_t)bz * NC;
    int quad = lane >> 4, colb = lane & 15;
    #pragma unroll
    for (int t = 0; t < 4; ++t) {
        int j = j0 + t * 16 + colb;
        #pragma unroll
        for (int rr = 0; rr < 4; ++rr) {
            int n = n0 + wv * 16 + quad * 4 + rr;
            size_t idx = (size_t)n * Cpad + j;
            pY[idx] = aY[t][rr];
            pS[idx] = aS[t][rr];
        }
    }
}

// K3: fused epilogue + row loss + mean. One block per row n: sum split-K
// partials, add bias, store y, isda logits in registers, logsumexp, then
// device-scope atomic accumulate of mean loss; last block writes out[0].
__global__ __launch_bounds__(256) void epilogue_rowloss(
        const float* __restrict__ partY, const float* __restrict__ partS,
        const float* __restrict__ T3p,
        const void* __restrict__ bias, const void* __restrict__ feat,
        const int* __restrict__ labels,
        void* __restrict__ out, size_t off_y,
        float* __restrict__ lsum, int* __restrict__ lcnt,
        int C, int Cpad, int A8, const void* ratio_p, size_t NC, int Nn) {
    __shared__ float sb[4];
    __shared__ float sM;
    __shared__ float sLabVal;
    int f32m = block_sniff(feat);
    int tid = threadIdx.x;
    int n = blockIdx.x;
    int lab = labels[n];
    float t3 = 0.f;
    for (int i = 0; i < A8; ++i) t3 += T3p[(size_t)lab * A8 + i];
    float ratio = decode_scalar(ratio_p);

    float vals[8];
    int nu = Cpad >> 8;        // <= 8 assumed (C <= 2048)
    float m = -3.4e38f;
    #pragma unroll
    for (int u = 0; u < 8; ++u) {     // static indexing: vals stays in registers
        float v = -3.4e38f;
        if (u < nu) {
            int j = u * 256 + tid;
            if (j < C) {
                size_t idx = (size_t)n * Cpad + j;
                float y = 0.f, s = 0.f;
                #pragma unroll
                for (int z = 0; z < KSPLIT; ++z) {
                    y += partY[z * NC + idx];
                    s += partS[z * NC + idx];
                }
                y += ldv(bias, j, f32m);
                stv(out, off_y + (size_t)n * C + j, y, f32m);
                v = y + 0.5f * ratio * (s + t3);
                if (j == lab) sLabVal = v;
            }
        }
        vals[u] = v;
        m = fmaxf(m, v);
    }
    // block max
    m = wave_max(m);
    int lane = tid & 63, wid = tid >> 6;
    if (lane == 0) sb[wid] = m;
    __syncthreads();
    if (tid == 0) sM = fmaxf(fmaxf(sb[0], sb[1]), fmaxf(sb[2], sb[3]));
    __syncthreads();
    m = sM;
    float s = 0.f;
    #pragma unroll
    for (int u = 0; u < 8; ++u) s += (u < nu) ? expf(vals[u] - m) : 0.f;   // -inf -> 0
    __syncthreads();
    s = wave_sum(s);
    if (lane == 0) sb[wid] = s;
    __syncthreads();
    if (tid == 0) {
        float rl = m + logf(sb[0] + sb[1] + sb[2] + sb[3]) - sLabVal;
        atomicAdd(lsum, rl);
        __threadfence();
        int old = atomicAdd(lcnt, 1);
        if (old == Nn - 1) {
            __threadfence();
            float total = atomicAdd(lsum, 0.f);   // coherent read via RMW
            stv(out, 0, total / (float)Nn, f32m);
        }
    }
}

extern "C" void kernel_launch(void* const* d_in, const int* in_sizes, int n_in,
                              void* d_out, int out_size, void* d_ws, size_t ws_size,
                              hipStream_t stream) {
    const void* feat   = d_in[0];
    const int*  labels = (const int*)d_in[1];
    const void* W      = d_in[2];
    const void* bias   = d_in[3];
    const void* ave    = d_in[4];
    const void* cov    = d_in[5];
    const void* amount = d_in[6];
    const void* ratiop = d_in[7];

    int NA = in_sizes[0];                  // N*A
    int Nn = in_sizes[1];                  // 512
    int C  = in_sizes[3];                  // 1000
    int A  = NA / Nn;                      // 2048
    int CA = in_sizes[2];                  // C*A
    int Cpad = ((C + 255) / 256) * 256;    // 1024
    int A8 = A / 512;                      // T3 chunks per class (512 cols/chunk)
    size_t NC = (size_t)Nn * Cpad;

    size_t off_y   = 1;
    size_t off_ave = off_y + (size_t)Nn * C;
    size_t off_cov = off_ave + (size_t)CA;
    size_t off_amt = off_cov + (size_t)CA;

    char* ws = (char*)d_ws;
    float* w_T3p  = (float*)ws;                        // C*A8 (<= 8192 floats reserved)
    float* w_lsum = w_T3p + 8192;                      // 1 (region reserves 1024)
    int*   w_lcnt = (int*)(w_lsum + 1);                // 1
    float* w_partY = w_lsum + 1024;                    // KSPLIT*NC
    float* w_partS = w_partY + KSPLIT * NC;            // KSPLIT*NC
    unsigned short* w_featb = (unsigned short*)(w_partS + KSPLIT * NC);   // NA
    unsigned short* w_Wb    = w_featb + NA;            // CA
    unsigned short* w_W2b   = w_Wb + CA;               // CA
    unsigned short* w_Cb    = w_W2b + CA;              // CA
    unsigned short* w_Gb    = w_Cb + CA;               // CA

    dim3 g1(A / 512, C);
    stats_prep<<<g1, 256, 0, stream>>>(feat, labels, ave, cov, amount, W,
                                       d_out, off_ave, off_cov, off_amt,
                                       w_featb, w_Wb, w_W2b, w_Cb, w_Gb,
                                       w_T3p, w_lsum, w_lcnt, Nn, A, A8, NA);
    // chunked XCD swizzle path requires exactly gx=16, gy=8, gz=4 (512 blocks)
    if (Cpad / 64 == 16 && Nn / 64 == 8 && KSPLIT == 4) {
        triple_gemm_mfma<1><<<dim3(512), 256, 0, stream>>>(
            feat, w_featb, w_Wb, w_W2b, w_Cb, w_Gb,
            labels, w_partY, w_partS, Cpad, A, NC);
    } else {
        dim3 g2(Cpad / 64, Nn / 64, KSPLIT);
        triple_gemm_mfma<0><<<g2, 256, 0, stream>>>(
            feat, w_featb, w_Wb, w_W2b, w_Cb, w_Gb,
            labels, w_partY, w_partS, Cpad, A, NC);
    }
    epilogue_rowloss<<<Nn, 256, 0, stream>>>(w_partY, w_partS, w_T3p,
                                             bias, feat, labels, d_out, off_y,
                                             w_lsum, w_lcnt,
                                             C, Cpad, A8, ratiop, NC, Nn);
}